// Round 1
// baseline (360.911 us; speedup 1.0000x reference)
//
#include <hip/hip_runtime.h>
#include <hip/hip_fp16.h>
#include <math.h>

// LinearCaps2d: capsule dynamic routing, BATCH=256, B_TYPES*H*W=2048 (=N), C=10, POSE=16, 3 iters.
// Strategy:
//   logits are linear in v:  logits_it = votes . (sum of previous v's)  -> no logits storage.
//   3 fused passes; each pass: recompute votes via MFMA f16, logits = votes.vsum (DPP reduce),
//   softmax over c (wave-local LDS), s += coeff*votes via second MFMA, global atomic flush.
// ws layout: s[256*10*16] , vsum[256*10*16]  (320 KB total)

typedef _Float16 f16;
typedef _Float16 f16x8 __attribute__((ext_vector_type(8)));
typedef float f32x4 __attribute__((ext_vector_type(4)));

#define DPP_ADD(v, ctrl) ((v) + __int_as_float(__builtin_amdgcn_update_dpp( \
    0, __float_as_int(v), (ctrl), 0xF, 0xF, true)))

// grid: 2048 blocks = 512 n-chunks (4 n each) x 4 b-groups (64 b each), 256 thr (4 waves)
// wave handles one 16-batch tile.
__global__ __launch_bounds__(256)
void pass_k(const float* __restrict__ poses, const float* __restrict__ weight,
            const float* __restrict__ vsum, float* __restrict__ s_out)
{
    // LDS: W [4n][10c][16o][24(16i+8pad)] f16 = 30720B ; x [64b][72(64+8pad)] f16 = 9216B
    //      cf per-wave [16b][44(40+4pad)] f32 = 11264B   -> total 51200B (~3 blocks/CU)
    __shared__ f16  Ws[4*10*16*24];
    __shared__ f16  xs[64*72];
    __shared__ float cfs[4][16*44];

    const int tid    = threadIdx.x;
    const int nchunk = blockIdx.x >> 2;
    const int bgrp   = blockIdx.x & 3;
    const int n0     = nchunk * 4;   // global n base
    const int b0     = bgrp * 64;    // global b base

    // ---- cooperative W load: 640 rows of 16 fp32 -> f16 LDS (padded rows of 24)
    for (int r = tid; r < 640; r += 256) {
        const int n_l = r / 160;
        const int rem = r - n_l * 160;               // c*16+o
        const float* gp = weight + ((size_t)(n0 + n_l) * 160 + rem) * 16;
        f16* lp = Ws + (n_l * 160 + rem) * 24;
        #pragma unroll
        for (int j = 0; j < 4; ++j) {
            float4 w = ((const float4*)gp)[j];
            lp[4*j+0] = (f16)w.x; lp[4*j+1] = (f16)w.y;
            lp[4*j+2] = (f16)w.z; lp[4*j+3] = (f16)w.w;
        }
    }
    // ---- cooperative x load: 64 b x 64 fp32 (4 n x 16 i)
    {
        const int b_loc = tid >> 2, part = tid & 3;  // part = one n (16 floats)
        const float* gp = poses + (size_t)(b0 + b_loc) * 32768 + (size_t)n0 * 16 + part * 16;
        f16* lp = xs + b_loc * 72 + part * 16;
        #pragma unroll
        for (int j = 0; j < 4; ++j) {
            float4 w = ((const float4*)gp)[j];
            lp[4*j+0] = (f16)w.x; lp[4*j+1] = (f16)w.y;
            lp[4*j+2] = (f16)w.z; lp[4*j+3] = (f16)w.w;
        }
    }
    __syncthreads();

    const int wave = tid >> 6;
    const int lane = tid & 63;
    const int q    = lane >> 4;     // k-group for A/B, row-group for C/D
    const int lo   = lane & 15;     // A row (b) / B col (o) / C col (o)
    const int wtb  = wave * 16;     // tile-local b base
    const int bg   = b0 + wtb;      // global b base of this wave's tile
    float* cf = cfs[wave];

    // vsum fragments in regs: vs[c][r] = vsum[b = bg+q*4+r][c][o = lo]
    float vs[10][4];
    #pragma unroll
    for (int c = 0; c < 10; ++c)
        #pragma unroll
        for (int r = 0; r < 4; ++r)
            vs[c][r] = vsum[((size_t)(bg + q*4 + r) * 10 + c) * 16 + lo];

    const f32x4 zf = {0.f, 0.f, 0.f, 0.f};
    f16x8 za = {0,0,0,0,0,0,0,0};
    const bool kglo = (q < 2);      // K=32 but i-dim is 16: upper k-groups are zero
    const int  i0a  = (q & 1) * 8;

    // ---- phase A: logits[b, c, n] = sum_o (X Wc^T)[b,o] * vsum[b,c,o]
    f16x8 a_n[4];
    #pragma unroll
    for (int n = 0; n < 4; ++n) {
        f16x8 ax = *(const f16x8*)&xs[(wtb + lo) * 72 + n * 16 + i0a];
        a_n[n] = kglo ? ax : za;
    }
    #pragma unroll
    for (int n = 0; n < 4; ++n) {
        #pragma unroll
        for (int c = 0; c < 10; ++c) {
            f16x8 bx = *(const f16x8*)&Ws[((n * 10 + c) * 16 + lo) * 24 + i0a];
            f16x8 bf = kglo ? bx : za;
            f32x4 V = __builtin_amdgcn_mfma_f32_16x16x32_f16(a_n[n], bf, zf, 0, 0, 0);
            float p0 = V[0] * vs[c][0];
            float p1 = V[1] * vs[c][1];
            float p2 = V[2] * vs[c][2];
            float p3 = V[3] * vs[c][3];
            // sum over the 16 o-lanes of each quad-row (row_ror 8/4/2/1)
            p0 = DPP_ADD(p0, 0x128); p0 = DPP_ADD(p0, 0x124); p0 = DPP_ADD(p0, 0x122); p0 = DPP_ADD(p0, 0x121);
            p1 = DPP_ADD(p1, 0x128); p1 = DPP_ADD(p1, 0x124); p1 = DPP_ADD(p1, 0x122); p1 = DPP_ADD(p1, 0x121);
            p2 = DPP_ADD(p2, 0x128); p2 = DPP_ADD(p2, 0x124); p2 = DPP_ADD(p2, 0x122); p2 = DPP_ADD(p2, 0x121);
            p3 = DPP_ADD(p3, 0x128); p3 = DPP_ADD(p3, 0x124); p3 = DPP_ADD(p3, 0x122); p3 = DPP_ADD(p3, 0x121);
            if (lo == 0) {
                cf[(q*4 + 0) * 44 + n * 10 + c] = p0;
                cf[(q*4 + 1) * 44 + n * 10 + c] = p1;
                cf[(q*4 + 2) * 44 + n * 10 + c] = p2;
                cf[(q*4 + 3) * 44 + n * 10 + c] = p3;
            }
        }
    }
    // wave-synchronous: LDS writes above and reads below are same-wave, compiler orders them.

    // ---- softmax over c, one (b,n) row per lane (64 rows = 16b x 4n)
    {
        const int rb = lane >> 2;
        const int rn = lane & 3;
        float l[10];
        #pragma unroll
        for (int c = 0; c < 10; ++c) l[c] = cf[rb * 44 + rn * 10 + c];
        float m = l[0];
        #pragma unroll
        for (int c = 1; c < 10; ++c) m = fmaxf(m, l[c]);
        float sum = 0.f;
        #pragma unroll
        for (int c = 0; c < 10; ++c) { l[c] = __expf(l[c] - m); sum += l[c]; }
        const float inv = 1.f / sum;
        #pragma unroll
        for (int c = 0; c < 10; ++c) cf[rb * 44 + rn * 10 + c] = l[c] * inv;
    }

    // ---- phase B: s[b,c,o] += sum_{n,i} (coeff[b,c,n]*x[b,n,i]) * W[n,c,o,i]  (K=32 = 2n x 16i)
    const int nl0 = q >> 1;
    const int i0b = (q & 1) * 8;
    #pragma unroll
    for (int c = 0; c < 10; ++c) {
        f32x4 acc = zf;
        #pragma unroll
        for (int np = 0; np < 2; ++np) {
            const int n_loc = np * 2 + nl0;
            f16x8 xa = *(const f16x8*)&xs[(wtb + lo) * 72 + n_loc * 16 + i0b];
            float cv = cf[lo * 44 + n_loc * 10 + c];
            f16 ch = (f16)cv;
            f16x8 av = xa * ch;
            f16x8 bw = *(const f16x8*)&Ws[((n_loc * 10 + c) * 16 + lo) * 24 + i0b];
            acc = __builtin_amdgcn_mfma_f32_16x16x32_f16(av, bw, acc, 0, 0, 0);
        }
        float* sp = s_out + ((size_t)(bg + q * 4) * 10 + c) * 16 + lo;
        unsafeAtomicAdd(sp + 0 * 160, acc[0]);
        unsafeAtomicAdd(sp + 1 * 160, acc[1]);
        unsafeAtomicAdd(sp + 2 * 160, acc[2]);
        unsafeAtomicAdd(sp + 3 * 160, acc[3]);
    }
}

// squash + vsum update (or final output). 2560 threads, one (b,c) each.
__global__ __launch_bounds__(256)
void squash_k(float* __restrict__ s, const float* __restrict__ bias,
              float* __restrict__ vsum, float* __restrict__ out, const int final_it)
{
    const int t = blockIdx.x * 256 + threadIdx.x;
    if (t >= 2560) return;
    const int c = t % 10;
    float* sp = s + (size_t)t * 16;
    const float* bp = bias + c * 16;
    float sv[16];
    float n2 = 0.f;
    #pragma unroll
    for (int o = 0; o < 16; ++o) { float v = sp[o] + bp[o]; sv[o] = v; n2 += v * v; }
    const float scale = n2 / (1.f + n2) * rsqrtf(n2 + 1e-8f);
    if (!final_it) {
        float* vp = vsum + (size_t)t * 16;
        #pragma unroll
        for (int o = 0; o < 16; ++o) { vp[o] += scale * sv[o]; sp[o] = 0.f; }  // zero s for next pass
    } else {
        float a2 = 0.f;
        #pragma unroll
        for (int o = 0; o < 16; ++o) {
            float v = scale * sv[o];
            out[(size_t)t * 16 + o] = v;
            a2 += v * v;
        }
        out[40960 + t] = sqrtf(a2 + 1e-8f);
    }
}

extern "C" void kernel_launch(void* const* d_in, const int* in_sizes, int n_in,
                              void* d_out, int out_size, void* d_ws, size_t ws_size,
                              hipStream_t stream)
{
    const float* poses  = (const float*)d_in[0];
    // d_in[1] (input_caps_activations) is unused by the reference.
    const float* weight = (const float*)d_in[2];
    const float* bias   = (const float*)d_in[3];
    float* out  = (float*)d_out;
    float* s    = (float*)d_ws;         // 40960 floats
    float* vsum = s + 40960;            // 40960 floats

    hipMemsetAsync(d_ws, 0, 2 * 40960 * sizeof(float), stream);  // s = 0, vsum = 0

    for (int it = 0; it < 3; ++it) {
        pass_k<<<2048, 256, 0, stream>>>(poses, weight, vsum, s);
        squash_k<<<10, 256, 0, stream>>>(s, bias, vsum, out, it == 2 ? 1 : 0);
    }
}

// Round 3
// 220.939 us; speedup vs baseline: 1.6335x; 1.6335x over previous
//
#include <hip/hip_runtime.h>
#include <hip/hip_fp16.h>
#include <math.h>

// LinearCaps2d: capsule dynamic routing, BATCH=256, N = B_TYPES*H*W = 2048, C=10, POSE=16, 3 iters.
// R3 = R2 with the W chunk-base fix (chunk stride is 10240 floats, not 2560).
//     n-loop register accumulation (L=4 n-chunks/block) -> atomic traffic /4,
//     software-pipelined staging loads, pass 0 specialization (coeff == 0.1 exactly).
// ws: s[40960] f32, vsum[40960] f32.

typedef _Float16 f16;
typedef _Float16 f16x8 __attribute__((ext_vector_type(8)));
typedef float f32x4 __attribute__((ext_vector_type(4)));

#define DPP_ADD(v, ctrl) ((v) + __int_as_float(__builtin_amdgcn_update_dpp( \
    0, __float_as_int(v), (ctrl), 0xF, 0xF, true)))

constexpr int LIT = 4;   // n-chunks per block (4 n each -> 16 n per block)

// grid: 512 blocks = 128 n-groups x 4 b-groups; 256 thr = 4 waves; wave owns a 16-batch tile.
template<int FIRST>
__global__ __launch_bounds__(256)
void pass_k(const float* __restrict__ poses, const float* __restrict__ weight,
            const float* __restrict__ vsum, float* __restrict__ s_out)
{
    // LDS: W [4n][160][24pad] f16 = 30720B ; x [64b][72pad] f16 = 9216B ; cf 4x[16][44] f32 = 11264B
    __shared__ f16  Ws[640 * 24];
    __shared__ f16  xs[64 * 72];
    __shared__ float cfs[4][16 * 44];

    const int tid  = threadIdx.x;
    const int ngrp = blockIdx.x >> 2;
    const int bgrp = blockIdx.x & 3;
    const int b0   = bgrp * 64;

    const int wave = tid >> 6;
    const int lane = tid & 63;
    const int q    = lane >> 4;
    const int lo   = lane & 15;
    const int wtb  = wave * 16;
    const int bg   = b0 + wtb;
    float* cf = cfs[wave];

    // ---- staging prefetch registers
    float4 wreg[10];
    float4 xreg[4];
    const int b_loc = tid >> 2, part = tid & 3;

    auto load_iter = [&](int l) {
        // one n-chunk = 4 n x 160 x 16 = 10240 floats  (R2 bug: used 2560)
        const float* wp = weight + (size_t)(ngrp * LIT + l) * 10240;
        #pragma unroll
        for (int k = 0; k < 10; ++k)
            wreg[k] = ((const float4*)wp)[tid + k * 256];
        const float* xp = poses + (size_t)(b0 + b_loc) * 32768 + (size_t)(ngrp * LIT + l) * 64 + part * 16;
        #pragma unroll
        for (int j = 0; j < 4; ++j)
            xreg[j] = ((const float4*)xp)[j];
    };
    auto store_iter = [&]() {
        #pragma unroll
        for (int k = 0; k < 10; ++k) {
            const int f = tid + k * 256;            // float4 index in [0,2560)
            f16* lp = Ws + (f >> 2) * 24 + (f & 3) * 4;
            lp[0] = (f16)wreg[k].x; lp[1] = (f16)wreg[k].y;
            lp[2] = (f16)wreg[k].z; lp[3] = (f16)wreg[k].w;
        }
        f16* lp = xs + b_loc * 72 + part * 16;
        #pragma unroll
        for (int j = 0; j < 4; ++j) {
            lp[4*j+0] = (f16)xreg[j].x; lp[4*j+1] = (f16)xreg[j].y;
            lp[4*j+2] = (f16)xreg[j].z; lp[4*j+3] = (f16)xreg[j].w;
        }
    };

    // vsum fragments (b,c,o fixed per wave; independent of n) — not needed on pass 0
    float vs[10][4];
    if (!FIRST) {
        #pragma unroll
        for (int c = 0; c < 10; ++c)
            #pragma unroll
            for (int r = 0; r < 4; ++r)
                vs[c][r] = vsum[((size_t)(bg + q*4 + r) * 10 + c) * 16 + lo];
    }

    const f32x4 zf = {0.f, 0.f, 0.f, 0.f};
    const f16x8 za = {0,0,0,0,0,0,0,0};
    const bool kglo = (q < 2);          // phase A uses K=32 with upper half zero
    const int  i0a  = (q & 1) * 8;
    const int  nl0  = q >> 1;           // phase B K packing: 2 n x 16 i
    const int  i0b  = (q & 1) * 8;

    f32x4 acc[10];
    #pragma unroll
    for (int c = 0; c < 10; ++c) acc[c] = zf;

    load_iter(0);

    for (int l = 0; l < LIT; ++l) {
        __syncthreads();                 // previous iteration's LDS consumers done
        store_iter();
        if (l + 1 < LIT) load_iter(l + 1);   // in flight during compute
        __syncthreads();                 // LDS tiles ready

        if (!FIRST) {
            // ---- phase A: logits[b,c,n] = sum_o votes[b,o] * vsum[b,c,o]
            f16x8 a_n[4];
            #pragma unroll
            for (int n = 0; n < 4; ++n) {
                f16x8 ax = *(const f16x8*)&xs[(wtb + lo) * 72 + n * 16 + i0a];
                a_n[n] = kglo ? ax : za;
            }
            #pragma unroll
            for (int n = 0; n < 4; ++n) {
                #pragma unroll
                for (int c = 0; c < 10; ++c) {
                    f16x8 bx = *(const f16x8*)&Ws[((n * 10 + c) * 16 + lo) * 24 + i0a];
                    f16x8 bf = kglo ? bx : za;
                    f32x4 V = __builtin_amdgcn_mfma_f32_16x16x32_f16(a_n[n], bf, zf, 0, 0, 0);
                    float p0 = V[0] * vs[c][0];
                    float p1 = V[1] * vs[c][1];
                    float p2 = V[2] * vs[c][2];
                    float p3 = V[3] * vs[c][3];
                    p0 = DPP_ADD(p0, 0x128); p0 = DPP_ADD(p0, 0x124); p0 = DPP_ADD(p0, 0x122); p0 = DPP_ADD(p0, 0x121);
                    p1 = DPP_ADD(p1, 0x128); p1 = DPP_ADD(p1, 0x124); p1 = DPP_ADD(p1, 0x122); p1 = DPP_ADD(p1, 0x121);
                    p2 = DPP_ADD(p2, 0x128); p2 = DPP_ADD(p2, 0x124); p2 = DPP_ADD(p2, 0x122); p2 = DPP_ADD(p2, 0x121);
                    p3 = DPP_ADD(p3, 0x128); p3 = DPP_ADD(p3, 0x124); p3 = DPP_ADD(p3, 0x122); p3 = DPP_ADD(p3, 0x121);
                    if (lo == 0) {
                        cf[(q*4 + 0) * 44 + n * 10 + c] = p0;
                        cf[(q*4 + 1) * 44 + n * 10 + c] = p1;
                        cf[(q*4 + 2) * 44 + n * 10 + c] = p2;
                        cf[(q*4 + 3) * 44 + n * 10 + c] = p3;
                    }
                }
            }
            // ---- softmax over c; one (b,n) row per lane (wave-synchronous LDS use)
            {
                const int rb = lane >> 2;
                const int rn = lane & 3;
                float lg[10];
                #pragma unroll
                for (int c = 0; c < 10; ++c) lg[c] = cf[rb * 44 + rn * 10 + c];
                float m = lg[0];
                #pragma unroll
                for (int c = 1; c < 10; ++c) m = fmaxf(m, lg[c]);
                float sum = 0.f;
                #pragma unroll
                for (int c = 0; c < 10; ++c) { lg[c] = __expf(lg[c] - m); sum += lg[c]; }
                const float inv = 1.f / sum;
                #pragma unroll
                for (int c = 0; c < 10; ++c) cf[rb * 44 + rn * 10 + c] = lg[c] * inv;
            }
        }

        // ---- phase B: acc[b,c,o] += sum_{n,i} (coeff*x)[b,(n,i)] * W[(n,i),c,o]  (K=32 = 2n x 16i)
        #pragma unroll
        for (int c = 0; c < 10; ++c) {
            #pragma unroll
            for (int np = 0; np < 2; ++np) {
                const int n_loc = np * 2 + nl0;
                f16x8 xa = *(const f16x8*)&xs[(wtb + lo) * 72 + n_loc * 16 + i0b];
                f16 ch;
                if (FIRST) ch = (f16)0.1f;
                else       ch = (f16)cf[lo * 44 + n_loc * 10 + c];
                f16x8 av = xa * ch;
                f16x8 bw = *(const f16x8*)&Ws[((n_loc * 10 + c) * 16 + lo) * 24 + i0b];
                acc[c] = __builtin_amdgcn_mfma_f32_16x16x32_f16(av, bw, acc[c], 0, 0, 0);
            }
        }
    }

    // ---- single atomic flush per block
    #pragma unroll
    for (int c = 0; c < 10; ++c) {
        float* sp = s_out + ((size_t)(bg + q * 4) * 10 + c) * 16 + lo;
        unsafeAtomicAdd(sp + 0 * 160, acc[c][0]);
        unsafeAtomicAdd(sp + 1 * 160, acc[c][1]);
        unsafeAtomicAdd(sp + 2 * 160, acc[c][2]);
        unsafeAtomicAdd(sp + 3 * 160, acc[c][3]);
    }
}

// squash + vsum update (or final output). 2560 threads, one (b,c) each.
__global__ __launch_bounds__(256)
void squash_k(float* __restrict__ s, const float* __restrict__ bias,
              float* __restrict__ vsum, float* __restrict__ out, const int final_it)
{
    const int t = blockIdx.x * 256 + threadIdx.x;
    if (t >= 2560) return;
    const int c = t % 10;
    float* sp = s + (size_t)t * 16;
    const float* bp = bias + c * 16;
    float sv[16];
    float n2 = 0.f;
    #pragma unroll
    for (int o = 0; o < 16; ++o) { float v = sp[o] + bp[o]; sv[o] = v; n2 += v * v; }
    const float scale = n2 / (1.f + n2) * rsqrtf(n2 + 1e-8f);
    if (!final_it) {
        float* vp = vsum + (size_t)t * 16;
        #pragma unroll
        for (int o = 0; o < 16; ++o) { vp[o] += scale * sv[o]; sp[o] = 0.f; }  // zero s for next pass
    } else {
        float a2 = 0.f;
        #pragma unroll
        for (int o = 0; o < 16; ++o) {
            float v = scale * sv[o];
            out[(size_t)t * 16 + o] = v;
            a2 += v * v;
        }
        out[40960 + t] = sqrtf(a2 + 1e-8f);
    }
}

extern "C" void kernel_launch(void* const* d_in, const int* in_sizes, int n_in,
                              void* d_out, int out_size, void* d_ws, size_t ws_size,
                              hipStream_t stream)
{
    const float* poses  = (const float*)d_in[0];
    // d_in[1] (input_caps_activations) unused by the reference.
    const float* weight = (const float*)d_in[2];
    const float* bias   = (const float*)d_in[3];
    float* out  = (float*)d_out;
    float* s    = (float*)d_ws;          // 40960 f32
    float* vsum = s + 40960;             // 40960 f32

    hipMemsetAsync(d_ws, 0, 2 * 40960 * sizeof(float), stream);  // s = 0, vsum = 0

    pass_k<1><<<512, 256, 0, stream>>>(poses, weight, vsum, s);
    squash_k<<<10, 256, 0, stream>>>(s, bias, vsum, out, 0);
    pass_k<0><<<512, 256, 0, stream>>>(poses, weight, vsum, s);
    squash_k<<<10, 256, 0, stream>>>(s, bias, vsum, out, 0);
    pass_k<0><<<512, 256, 0, stream>>>(poses, weight, vsum, s);
    squash_k<<<10, 256, 0, stream>>>(s, bias, vsum, out, 1);
}

// Round 7
// 204.655 us; speedup vs baseline: 1.7635x; 1.0796x over previous
//
#include <hip/hip_runtime.h>
#include <hip/hip_fp16.h>
#include <math.h>

// LinearCaps2d, BATCH=256, N = B_TYPES*H*W = 2048, C=10, POSE=16, 3 routing iters.
// R7 = R6's compute restructure with plain (non-cooperative) launches.
//   logits linear in v: logits_p = votes . vsum_p ; vsum recomputed inline from s buffers.
//   Phase A transposed (A=W,B=x -> D[o][b]): o-reduce = 2 fdot2 + 2 shfl_xor; per-lane softmax.
//   Phase B (verified R3): K=32 packs 2 n, acc over 4 n-chunks, one atomic flush per pass.
// ws: s0,s1,s2 [40960] f32 each.

typedef _Float16 f16;
typedef _Float16 f16x2 __attribute__((ext_vector_type(2)));
typedef _Float16 f16x4 __attribute__((ext_vector_type(4)));
typedef _Float16 f16x8 __attribute__((ext_vector_type(8)));
typedef __fp16   h16x2 __attribute__((ext_vector_type(2)));
typedef float f32x4 __attribute__((ext_vector_type(4)));

#define DPP_ADD(v, ctrl) ((v) + __int_as_float(__builtin_amdgcn_update_dpp( \
    0, __float_as_int(v), (ctrl), 0xF, 0xF, true)))

__device__ __forceinline__ f16x2 pk(float a, float b) {
    h16x2 t = __builtin_amdgcn_cvt_pkrtz(a, b);
    return __builtin_bit_cast(f16x2, t);
}

#if __has_builtin(__builtin_amdgcn_fdot2)
__device__ __forceinline__ float FDOT2(f16x2 a, f16x2 b, float c) {
    return __builtin_amdgcn_fdot2(__builtin_bit_cast(h16x2, a),
                                  __builtin_bit_cast(h16x2, b), c, false);
}
#else
__device__ __forceinline__ float FDOT2(f16x2 a, f16x2 b, float c) {
    return c + (float)a[0] * (float)b[0] + (float)a[1] * (float)b[1];
}
#endif

constexpr int WS_ROW = 28;   // f16 stride, Ws row = 16 i + pad (56 B)
constexpr int XS_ROW = 76;   // f16 stride, xs row = 64 (4n x 16i) + pad (152 B)

__device__ __forceinline__ float xorsum4(float v) {
    v += __shfl_xor(v, 16, 64);
    v += __shfl_xor(v, 32, 64);
    return v;
}

__device__ __forceinline__ f16x4 cvt4(float4 w) {
    f16x2 a = pk(w.x, w.y);
    f16x2 b = pk(w.z, w.w);
    f16x4 r; r[0] = a[0]; r[1] = a[1]; r[2] = b[0]; r[3] = b[1];
    return r;
}

// grid: 512 blocks = 128 n-groups (16 n) x 4 b-groups (64 b); 256 thr = 4 waves.
template<int PASS>
__global__ __launch_bounds__(256)
void pass_k(const float* __restrict__ poses, const float* __restrict__ weight,
            const float* __restrict__ bias,
            const float* __restrict__ sp0, const float* __restrict__ sp1,
            float* __restrict__ s_dst)
{
    __shared__ f16 Ws[640 * WS_ROW];   // 35840 B
    __shared__ f16 xs[64 * XS_ROW];    //  9728 B

    const int tid  = threadIdx.x;
    const int blk  = blockIdx.x;
    const int ngrp = blk >> 2;          // 128 n-groups (16 n each)
    const int b0   = (blk & 3) * 64;    // 4 b-groups (64 b each)
    const int wave = tid >> 6;
    const int lane = tid & 63;
    const int q    = lane >> 4;
    const int lo   = lane & 15;
    const int wtb  = wave * 16;
    const int bg   = b0 + wtb;          // wave's global batch base
    const int nl0  = q >> 1;            // phase B: which n of the K-pair
    const int iq   = (q & 1) * 8;       // phase B: i offset within n

    // ---- inline squash: vsum fragment vsp[c] = (v at o=q*4..q*4+3), b = bg+lo, packed f16
    f16x2 vsp[10][2];
    if (PASS >= 1) {
        const int rowb = (bg + lo) * 10;
        #pragma unroll
        for (int c = 0; c < 10; ++c) {
            float4 bb = *(const float4*)(bias + c * 16 + q * 4);
            float4 sa = *(const float4*)(sp0 + (size_t)(rowb + c) * 16 + q * 4);
            float t0 = sa.x + bb.x, t1 = sa.y + bb.y, t2 = sa.z + bb.z, t3 = sa.w + bb.w;
            float n2 = xorsum4(t0*t0 + t1*t1 + t2*t2 + t3*t3);
            float sc = n2 / (1.f + n2) * rsqrtf(n2 + 1e-8f);
            float v0 = sc*t0, v1 = sc*t1, v2 = sc*t2, v3 = sc*t3;
            if (PASS == 2) {
                float4 sb = *(const float4*)(sp1 + (size_t)(rowb + c) * 16 + q * 4);
                float u0 = sb.x + bb.x, u1 = sb.y + bb.y, u2 = sb.z + bb.z, u3 = sb.w + bb.w;
                float m2 = xorsum4(u0*u0 + u1*u1 + u2*u2 + u3*u3);
                float sc2 = m2 / (1.f + m2) * rsqrtf(m2 + 1e-8f);
                v0 += sc2*u0; v1 += sc2*u1; v2 += sc2*u2; v3 += sc2*u3;
            }
            vsp[c][0] = pk(v0, v1);
            vsp[c][1] = pk(v2, v3);
        }
    }

    // ---- staging (software-pipelined)
    float4 wreg[10];
    float4 xreg[4];
    const int b_loc = tid >> 2, part = tid & 3;

    auto load_iter = [&](int l) {
        const float* wp = weight + (size_t)(ngrp * 4 + l) * 10240;   // 4n x 160 x 16
        #pragma unroll
        for (int k = 0; k < 10; ++k) wreg[k] = ((const float4*)wp)[tid + k * 256];
        const float* xp = poses + (size_t)(b0 + b_loc) * 32768
                          + (size_t)(ngrp * 16 + l * 4 + part) * 16;
        #pragma unroll
        for (int j = 0; j < 4; ++j) xreg[j] = ((const float4*)xp)[j];
    };
    auto store_iter = [&]() {
        #pragma unroll
        for (int k = 0; k < 10; ++k) {
            const int f = tid + k * 256;         // float4 index in [0,2560)
            *(f16x4*)&Ws[(f >> 2) * WS_ROW + (f & 3) * 4] = cvt4(wreg[k]);
        }
        f16* lp = xs + b_loc * XS_ROW + part * 16;
        #pragma unroll
        for (int j = 0; j < 4; ++j) *(f16x4*)&lp[j * 4] = cvt4(xreg[j]);
    };

    f32x4 acc[10];
    #pragma unroll
    for (int c = 0; c < 10; ++c) acc[c] = (f32x4){0.f, 0.f, 0.f, 0.f};

    f16x2 cf[10][2];   // coeff packed over n-pairs: cf[c][np] = (coeff[n=2np], coeff[n=2np+1])

    load_iter(0);

    for (int l = 0; l < 4; ++l) {
        __syncthreads();
        store_iter();
        if (l + 1 < 4) load_iter(l + 1);
        __syncthreads();

        if (PASS >= 1) {
            // ---- phase A: votes^T via 16x16x16 MFMA (D[o][b]); logits via fdot2 + shfl
            float ce[10];
            #pragma unroll
            for (int n = 0; n < 4; ++n) {
                f16x4 bx = *(const f16x4*)&xs[(wtb + lo) * XS_ROW + n * 16 + q * 4];
                float lg[10];
                #pragma unroll
                for (int c = 0; c < 10; ++c) {
                    f16x4 aw = *(const f16x4*)&Ws[((n * 10 + c) * 16 + lo) * WS_ROW + q * 4];
                    f32x4 D = __builtin_amdgcn_mfma_f32_16x16x16f16(
                        aw, bx, (f32x4){0.f, 0.f, 0.f, 0.f}, 0, 0, 0);
                    float p = FDOT2(pk(D[0], D[1]), vsp[c][0], 0.f);
                    p = FDOT2(pk(D[2], D[3]), vsp[c][1], p);
                    lg[c] = xorsum4(p);      // logits[b=bg+lo][n][c], replicated over q
                }
                // per-lane softmax over c
                float m = lg[0];
                #pragma unroll
                for (int c = 1; c < 10; ++c) m = fmaxf(m, lg[c]);
                float sum = 0.f;
                #pragma unroll
                for (int c = 0; c < 10; ++c) { lg[c] = __expf(lg[c] - m); sum += lg[c]; }
                const float inv = 1.f / sum;
                if (n & 1) {
                    #pragma unroll
                    for (int c = 0; c < 10; ++c)
                        cf[c][n >> 1] = pk(ce[c], lg[c] * inv);
                } else {
                    #pragma unroll
                    for (int c = 0; c < 10; ++c) ce[c] = lg[c] * inv;
                }
            }
        }

        // ---- phase B: acc[b,c,o] += (coeff*x) W  (K=32 = 2n x 16i)
        f16x8 xa[2];
        #pragma unroll
        for (int np = 0; np < 2; ++np) {
            const f16* p = &xs[(wtb + lo) * XS_ROW + (np * 2 + nl0) * 16 + iq];
            f16x4 x0 = *(const f16x4*)p;
            f16x4 x1 = *(const f16x4*)(p + 4);
            xa[np] = __builtin_shufflevector(x0, x1, 0, 1, 2, 3, 4, 5, 6, 7);
        }
        #pragma unroll
        for (int c = 0; c < 10; ++c) {
            #pragma unroll
            for (int np = 0; np < 2; ++np) {
                f16 ch;
                if (PASS == 0) {
                    ch = (f16)0.1f;
                } else {
                    union { f16x2 h; unsigned u; } cu; cu.h = cf[c][np];
                    unsigned hv = nl0 ? (cu.u >> 16) : (cu.u & 0xffffu);
                    union { unsigned short s; f16 h; } hu; hu.s = (unsigned short)hv;
                    ch = hu.h;
                }
                const int n_loc = np * 2 + nl0;
                const f16* wp_ = &Ws[((n_loc * 10 + c) * 16 + lo) * WS_ROW + iq];
                f16x4 w0 = *(const f16x4*)wp_;
                f16x4 w1 = *(const f16x4*)(wp_ + 4);
                f16x8 bw = __builtin_shufflevector(w0, w1, 0, 1, 2, 3, 4, 5, 6, 7);
                f16x8 av = xa[np] * ch;
                acc[c] = __builtin_amdgcn_mfma_f32_16x16x32_f16(av, bw, acc[c], 0, 0, 0);
            }
        }
    }

    // ---- atomic flush (rows b = bg+q*4+r, col o = lo)
    #pragma unroll
    for (int c = 0; c < 10; ++c) {
        float* sp = s_dst + ((size_t)(bg + q * 4) * 10 + c) * 16 + lo;
        unsafeAtomicAdd(sp + 0 * 160, acc[c][0]);
        unsafeAtomicAdd(sp + 1 * 160, acc[c][1]);
        unsafeAtomicAdd(sp + 2 * 160, acc[c][2]);
        unsafeAtomicAdd(sp + 3 * 160, acc[c][3]);
    }
}

// final squash: 2560 rows, one (b,c) per thread (verified in R3).
__global__ __launch_bounds__(256)
void epi_k(const float* __restrict__ s2, const float* __restrict__ bias,
           float* __restrict__ out)
{
    const int t = blockIdx.x * 256 + threadIdx.x;
    if (t >= 2560) return;
    const int c = t % 10;
    const float* sp = s2 + (size_t)t * 16;
    const float* bp = bias + c * 16;
    float sv[16];
    float n2 = 0.f;
    #pragma unroll
    for (int o = 0; o < 16; ++o) { float v = sp[o] + bp[o]; sv[o] = v; n2 += v * v; }
    const float scale = n2 / (1.f + n2) * rsqrtf(n2 + 1e-8f);
    float a2 = 0.f;
    #pragma unroll
    for (int o = 0; o < 16; ++o) {
        float v = scale * sv[o];
        out[(size_t)t * 16 + o] = v;
        a2 += v * v;
    }
    out[40960 + t] = sqrtf(a2 + 1e-8f);
}

extern "C" void kernel_launch(void* const* d_in, const int* in_sizes, int n_in,
                              void* d_out, int out_size, void* d_ws, size_t ws_size,
                              hipStream_t stream)
{
    const float* poses  = (const float*)d_in[0];
    // d_in[1] (input_caps_activations) unused by the reference.
    const float* weight = (const float*)d_in[2];
    const float* bias   = (const float*)d_in[3];
    float* out = (float*)d_out;
    float* s0 = (float*)d_ws;
    float* s1 = s0 + 40960;
    float* s2 = s1 + 40960;

    (void)hipMemsetAsync(d_ws, 0, 3 * 40960 * sizeof(float), stream);

    pass_k<0><<<512, 256, 0, stream>>>(poses, weight, bias, nullptr, nullptr, s0);
    pass_k<1><<<512, 256, 0, stream>>>(poses, weight, bias, s0, nullptr, s1);
    pass_k<2><<<512, 256, 0, stream>>>(poses, weight, bias, s0, s1, s2);
    epi_k<<<10, 256, 0, stream>>>(s2, bias, out);
}